// Round 15
// baseline (90.761 us; speedup 1.0000x reference)
//
#include <hip/hip_runtime.h>

typedef __bf16 bf16x8 __attribute__((ext_vector_type(8)));
typedef float f32x4 __attribute__((ext_vector_type(4)));

#define MFMA(a, b, c) __builtin_amdgcn_mfma_f32_16x16x32_bf16(a, b, c, 0, 0, 0)

#define CS 0.18033688011112042f   /* 0.125 * log2(e) */

__device__ __forceinline__ ushort f2bf(float f) {
    __bf16 h = (__bf16)f;
    return *(ushort*)&h;
}
__device__ __forceinline__ float bf2f(ushort u) {
    unsigned int x = ((unsigned int)u) << 16;
    return __uint_as_float(x);
}

// ---- stage (8*nchunks)-row x 64-col bf16 tile into LDS, XOR-swizzled (128B rows)
__device__ __forceinline__ void stage_tile64(ushort* lds, const ushort* gbase,
                                             int row_stride, int nchunks,
                                             int wave, int lane) {
    int r8 = lane >> 3;
    int cswz = ((lane & 7) ^ r8) << 4;
#pragma unroll
    for (int c = wave; c < nchunks; c += 4) {
        const char* g = (const char*)(gbase + (size_t)(c * 8 + r8) * row_stride) + cswz;
        __builtin_amdgcn_global_load_lds(
            (const __attribute__((address_space(1))) unsigned int*)g,
            (__attribute__((address_space(3))) unsigned int*)((char*)lds + c * 1024),
            16, 0, 0);
    }
}

__device__ __forceinline__ bf16x8 lds_read_row(const ushort* lds, int row, int cb) {
    return *(const bf16x8*)((const char*)lds + row * 128 + (cb ^ ((row & 7) << 4)));
}

// ---- stage (16*nchunks)-row x 32-col bf16 tile into LDS, XOR-swizzled (64B rows)
__device__ __forceinline__ void stage_tile32(ushort* lds, const ushort* gbase,
                                             int row_stride, int nchunks,
                                             int wave, int lane) {
    int r16 = lane >> 2;
    int csw = (((lane & 3) ^ ((lane >> 3) & 3)) << 3);
#pragma unroll
    for (int c = wave; c < nchunks; c += 4) {
        const ushort* g = gbase + (size_t)(c * 16 + r16) * row_stride + csw;
        __builtin_amdgcn_global_load_lds(
            (const __attribute__((address_space(1))) unsigned int*)g,
            (__attribute__((address_space(3))) unsigned int*)((char*)lds + c * 1024),
            16, 0, 0);
    }
}

__device__ __forceinline__ bf16x8 lds_read_row32(const ushort* lds, int row, int cb) {
    return *(const bf16x8*)((const char*)lds + row * 64 + (cb ^ (((row >> 1) & 3) << 4)));
}

// ---------------------------------------------------------------- groupnorm (+fused weight cvt)
__global__ __launch_bounds__(256) void gn_cvt_kernel(const float* __restrict__ x,
                                                     const float* __restrict__ gnw,
                                                     const float* __restrict__ gnb,
                                                     ushort* __restrict__ hnT,
                                                     const float* __restrict__ w1,
                                                     const float* __restrict__ w2,
                                                     ushort* __restrict__ o1,
                                                     ushort* __restrict__ o2) {
    __shared__ ushort xcache[16 * 1028];   // ~32.1 KB
    __shared__ float red[8];
    __shared__ float sw[16], sb[16];

    if (blockIdx.x >= 256) {
        int t = (blockIdx.x - 256) * 256 + threadIdx.x;
        const int n1q = (1536 * 512) / 4;
        float4 v;
        ushort* dst;
        int idx;
        if (t < n1q) {
            v = ((const float4*)w1)[t]; dst = o1; idx = t;
        } else {
            idx = t - n1q;
            v = ((const float4*)w2)[idx]; dst = o2;
        }
        ushort4 p;
        p.x = f2bf(v.x); p.y = f2bf(v.y); p.z = f2bf(v.z); p.w = f2bf(v.w);
        ((ushort4*)dst)[idx] = p;
        return;
    }

    int b = blockIdx.x >> 5, g = blockIdx.x & 31;
    const float* xp = x + (size_t)(b * 512 + g * 16) * 1024;
    int t = threadIdx.x;

    float s = 0.f, ss = 0.f;
    const float4* xp4 = (const float4*)xp;
    for (int i = t; i < 4096; i += 256) {
        float4 v = xp4[i];
        s += (v.x + v.y) + (v.z + v.w);
        ss += (v.x * v.x + v.y * v.y) + (v.z * v.z + v.w * v.w);
        int f = i * 4;
        int cc = f >> 10, nl = f & 1023;
        ushort4 c;
        c.x = f2bf(v.x); c.y = f2bf(v.y); c.z = f2bf(v.z); c.w = f2bf(v.w);
        *(ushort4*)&xcache[cc * 1028 + nl] = c;
    }
#pragma unroll
    for (int off = 32; off >= 1; off >>= 1) {
        s += __shfl_xor(s, off);
        ss += __shfl_xor(ss, off);
    }
    int wave = t >> 6;
    if ((t & 63) == 0) { red[wave] = s; red[wave + 4] = ss; }
    if (t < 16) { sw[t] = gnw[g * 16 + t]; sb[t] = gnb[g * 16 + t]; }
    __syncthreads();
    float S = red[0] + red[1] + red[2] + red[3];
    float SS = red[4] + red[5] + red[6] + red[7];
    float mean = S * (1.0f / 16384.0f);
    float var = SS * (1.0f / 16384.0f) - mean * mean;
    float rstd = rsqrtf(var + 1e-5f);

    int cc0 = (t & 3) * 4;
    int nb = t >> 2;
    float w0 = sw[cc0] * rstd, w1_ = sw[cc0 + 1] * rstd,
          w2_ = sw[cc0 + 2] * rstd, w3 = sw[cc0 + 3] * rstd;
    float b0 = sb[cc0] - mean * w0, b1 = sb[cc0 + 1] - mean * w1_,
          b2 = sb[cc0 + 2] - mean * w2_, b3 = sb[cc0 + 3] - mean * w3;
#pragma unroll
    for (int k = 0; k < 16; ++k) {
        int nl = nb + 64 * k;
        ushort4 p;
        p.x = f2bf(bf2f(xcache[(cc0 + 0) * 1028 + nl]) * w0 + b0);
        p.y = f2bf(bf2f(xcache[(cc0 + 1) * 1028 + nl]) * w1_ + b1);
        p.z = f2bf(bf2f(xcache[(cc0 + 2) * 1028 + nl]) * w2_ + b2);
        p.w = f2bf(bf2f(xcache[(cc0 + 3) * 1028 + nl]) * w3 + b3);
        *(ushort4*)(hnT + ((size_t)b * 1024 + nl) * 512 + g * 16 + cc0) = p;
    }
}

// ---------------------------------------------------------------- QKV GEMM
// BK=32, triple-buffered ring (48KB -> 3 blocks/CU), counted-vmcnt pipeline.
// V written kv-permuted (pi^-1) for attention's in-register P; Q pre-scaled.
__global__ __launch_bounds__(256, 3) void gemm_qkv(const ushort* __restrict__ Wb,
                                                   const ushort* __restrict__ hnT,
                                                   const float* __restrict__ qkvb,
                                                   ushort* __restrict__ qT,
                                                   ushort* __restrict__ kT,
                                                   ushort* __restrict__ vb) {
    int lane = threadIdx.x & 63, wave = threadIdx.x >> 6;
    int l15 = lane & 15, lg = lane >> 4;
    int bi = blockIdx.x;
    int b = bi & 7;
    int slot = bi >> 3;
    int m0 = (slot % 12) * 128;
    int n0 = (slot / 12) * 128;
    int mw = (wave >> 1) * 64, nw = (wave & 1) * 64;
    const ushort* Ag = Wb + (size_t)m0 * 512;
    const ushort* Bg = hnT + (size_t)b * 524288 + (size_t)n0 * 512;

    __shared__ ushort abuf[3][4096];
    __shared__ ushort bbuf[3][4096];

    f32x4 acc[4][4] = {};
#pragma unroll
    for (int p = 0; p < 2; ++p) {
        stage_tile32(abuf[p], Ag + p * 32, 512, 8, wave, lane);
        stage_tile32(bbuf[p], Bg + p * 32, 512, 8, wave, lane);
    }
    asm volatile("s_waitcnt vmcnt(4)" ::: "memory");
    __builtin_amdgcn_s_barrier();

    int cur = 0;
#pragma unroll 1
    for (int t = 0; t < 16; ++t) {
        if (t < 14) {
            int nxt = cur + 2; if (nxt >= 3) nxt -= 3;
            stage_tile32(abuf[nxt], Ag + (t + 2) * 32, 512, 8, wave, lane);
            stage_tile32(bbuf[nxt], Bg + (t + 2) * 32, 512, 8, wave, lane);
        }
        const ushort* A = abuf[cur];
        const ushort* B = bbuf[cur];
        bf16x8 af[4], bfr[4];
#pragma unroll
        for (int i = 0; i < 4; i++)
            af[i] = lds_read_row32(A, mw + i * 16 + l15, lg * 16);
#pragma unroll
        for (int j = 0; j < 4; j++)
            bfr[j] = lds_read_row32(B, nw + j * 16 + l15, lg * 16);
        __builtin_amdgcn_s_setprio(1);
#pragma unroll
        for (int i = 0; i < 4; i++)
#pragma unroll
            for (int j = 0; j < 4; j++)
                acc[i][j] = MFMA(af[i], bfr[j], acc[i][j]);
        __builtin_amdgcn_s_setprio(0);
        if (t < 15) {
            if (t < 14) asm volatile("s_waitcnt vmcnt(4)" ::: "memory");
            else        asm volatile("s_waitcnt vmcnt(0)" ::: "memory");
            __builtin_amdgcn_s_barrier();
        }
        cur = cur + 1; if (cur == 3) cur = 0;
    }

#pragma unroll
    for (int i = 0; i < 4; i++) {
        int ob = m0 + mw + i * 16 + lg * 4;
        float bias[4];
#pragma unroll
        for (int r = 0; r < 4; r++) bias[r] = qkvb[ob + r];
        int part = ob >> 9;
        int oo = ob & 511;
#pragma unroll
        for (int j = 0; j < 4; j++) {
            int n = n0 + nw + j * 16 + l15;
            if (part == 2) {
                int L = n & 63;
                int cf = L >> 4;
                int s = ((cf >> 1) << 5) | (((L >> 2) & 3) << 3) | ((cf & 1) << 2) | (L & 3);
                int np = (n & ~63) | s;
#pragma unroll
                for (int r = 0; r < 4; r++)
                    vb[(size_t)(b * 512 + oo + r) * 1024 + np] = f2bf(acc[i][j][r] + bias[r]);
            } else {
                ushort* dst = part ? kT : qT;
                float sc = part ? 1.0f : CS;
                int h = oo >> 6, dd = oo & 63;
                ushort4 p;
                p.x = f2bf((acc[i][j][0] + bias[0]) * sc);
                p.y = f2bf((acc[i][j][1] + bias[1]) * sc);
                p.z = f2bf((acc[i][j][2] + bias[2]) * sc);
                p.w = f2bf((acc[i][j][3] + bias[3]) * sc);
                *(ushort4*)(dst + ((size_t)((b * 8 + h) * 1024 + n)) * 64 + dd) = p;
            }
        }
    }
}

// ---------------------------------------------------------------- attention
// 128 q-rows/block; 4 waves = 2 q-groups (64 rows each) x 2 KV-HALVES.
// Wave (qg,kvh) processes kv-tiles {2s+kvh}: K/V fragments read from LDS once
// per wave per tile and reused over 4 i-tiles (R14's intensity) while keeping
// 8 waves/CU (R13's occupancy). No running max -> the kv-split combine is
// exact: O = O_even + O_odd, l = l_even + l_odd, done once via an LDS overlay
// on the dead K/V ring. 4-buffer ring, stage tiles 2s+2,2s+3 per group,
// vmcnt(0)+barrier per group (full 2-tile compute of prefetch cover).
// Swapped QK^T keeps P in registers (V kv-permuted by pi^-1 in gemm_qkv).
// Q pre-scaled: P = exp2(S). Row sums via ones-MFMA.
__global__ __launch_bounds__(256) void attn_kernel(const ushort* __restrict__ qT,
                                                   const ushort* __restrict__ kT,
                                                   const ushort* __restrict__ vb,
                                                   ushort* __restrict__ aoT) {
    int bi = blockIdx.x;
    int bh = ((bi >> 6) << 3) | (bi & 7);
    int q0 = ((bi >> 3) & 7) * 128;
    int b = bh >> 3, h = bh & 7;
    int lane = threadIdx.x & 63, wave = threadIdx.x >> 6;   // 0..3
    int l15 = lane & 15, lg = lane >> 4;
    int qg = wave & 1, kvh = wave >> 1;
    const ushort* qp = qT + (size_t)bh * 65536;
    const ushort* kp = kT + (size_t)bh * 65536;
    const ushort* vp = vb + (size_t)bh * 65536;

    __shared__ char smem[65536];
    ushort* kbuf = (ushort*)smem;            // 4 slots x 4096 ushorts (32 KB)
    ushort* vbuf = (ushort*)(smem + 32768);  // 4 slots x 4096 ushorts (32 KB)
    float*  comb = (float*)smem;             // epilogue overlay (40 KB)

    bf16x8 vone;
#pragma unroll
    for (int e = 0; e < 8; e++) vone[e] = (__bf16)1.0f;

    int qbase = q0 + qg * 64;
    bf16x8 qf[4][2];
#pragma unroll
    for (int i = 0; i < 4; i++)
#pragma unroll
        for (int kh = 0; kh < 2; kh++)
            qf[i][kh] = *(const bf16x8*)(qp + (size_t)(qbase + i * 16 + l15) * 64 + kh * 32 + lg * 8);

    f32x4 oacc[4][4] = {};
    f32x4 lacc[4] = {};

    // prologue: stage tiles 0,1 (all 4 waves cooperate; 8 loads/wave)
    stage_tile64(kbuf, kp, 64, 8, wave, lane);
    stage_tile64(vbuf, vp, 1024, 8, wave, lane);
    stage_tile64(kbuf + 4096, kp + 4096, 64, 8, wave, lane);
    stage_tile64(vbuf + 4096, vp + 64, 1024, 8, wave, lane);
    asm volatile("s_waitcnt vmcnt(0)" ::: "memory");
    __builtin_amdgcn_s_barrier();

#pragma unroll 1
    for (int s = 0; s < 8; ++s) {
        if (s < 7) {
            int t2 = 2 * s + 2, t3 = 2 * s + 3;
            stage_tile64(kbuf + (t2 & 3) * 4096, kp + (size_t)t2 * 4096, 64, 8, wave, lane);
            stage_tile64(vbuf + (t2 & 3) * 4096, vp + t2 * 64, 1024, 8, wave, lane);
            stage_tile64(kbuf + (t3 & 3) * 4096, kp + (size_t)t3 * 4096, 64, 8, wave, lane);
            stage_tile64(vbuf + (t3 & 3) * 4096, vp + t3 * 64, 1024, 8, wave, lane);
        }
        int t = 2 * s + kvh;
        const ushort* kb = kbuf + (t & 3) * 4096;
        const ushort* vc = vbuf + (t & 3) * 4096;

        // K/V fragments read ONCE, reused across 4 i-tiles
        bf16x8 kf[2][4], vf[2][4];
#pragma unroll
        for (int kh = 0; kh < 2; kh++)
#pragma unroll
            for (int cf = 0; cf < 4; cf++)
                kf[kh][cf] = lds_read_row(kb, cf * 16 + l15, kh * 64 + lg * 16);
#pragma unroll
        for (int ks = 0; ks < 2; ks++)
#pragma unroll
            for (int cf = 0; cf < 4; cf++)
                vf[ks][cf] = lds_read_row(vc, cf * 16 + l15, ks * 64 + lg * 16);

#pragma unroll
        for (int ih = 0; ih < 2; ih++) {
            f32x4 sacc[2][4] = {};
            __builtin_amdgcn_s_setprio(1);
#pragma unroll
            for (int kh = 0; kh < 2; kh++)
#pragma unroll
                for (int cf = 0; cf < 4; cf++) {
                    sacc[0][cf] = MFMA(kf[kh][cf], qf[2 * ih + 0][kh], sacc[0][cf]);
                    sacc[1][cf] = MFMA(kf[kh][cf], qf[2 * ih + 1][kh], sacc[1][cf]);
                }
            __builtin_amdgcn_s_setprio(0);

            bf16x8 pa[2][2];
#pragma unroll
            for (int ii = 0; ii < 2; ii++)
#pragma unroll
                for (int ks = 0; ks < 2; ks++) {
                    bf16x8 tr;
#pragma unroll
                    for (int jhi = 0; jhi < 2; jhi++)
#pragma unroll
                        for (int r = 0; r < 4; r++)
                            tr[jhi * 4 + r] = (__bf16)exp2f(sacc[ii][ks * 2 + jhi][r]);
                    pa[ii][ks] = tr;
                }

            __builtin_amdgcn_s_setprio(1);
#pragma unroll
            for (int ii = 0; ii < 2; ii++)
#pragma unroll
                for (int ks = 0; ks < 2; ks++) {
                    lacc[2 * ih + ii] = MFMA(pa[ii][ks], vone, lacc[2 * ih + ii]);
#pragma unroll
                    for (int cf = 0; cf < 4; cf++)
                        oacc[2 * ih + ii][cf] = MFMA(pa[ii][ks], vf[ks][cf], oacc[2 * ih + ii][cf]);
                }
            __builtin_amdgcn_s_setprio(0);
        }

        if (s < 7) {
            asm volatile("s_waitcnt vmcnt(0)" ::: "memory");
            __builtin_amdgcn_s_barrier();
        }
    }

    // ---- combine kv-halves: overlay comb on the (now dead) K/V ring ----
    __builtin_amdgcn_s_barrier();          // all waves done reading kbuf/vbuf
    if (kvh == 1) {
        float* dst = comb + qg * 5120;     // 20 slots x 256 floats per qg
#pragma unroll
        for (int i = 0; i < 4; i++)
#pragma unroll
            for (int cf = 0; cf < 4; cf++)
                *(f32x4*)(dst + (i * 4 + cf) * 256 + lane * 4) = oacc[i][cf];
#pragma unroll
        for (int i = 0; i < 4; i++)
            *(f32x4*)(dst + (16 + i) * 256 + lane * 4) = lacc[i];
    }
    __builtin_amdgcn_s_barrier();
    if (kvh == 0) {
        const float* src = comb + qg * 5120;
#pragma unroll
        for (int i = 0; i < 4; i++)
#pragma unroll
            for (int cf = 0; cf < 4; cf++)
                oacc[i][cf] += *(const f32x4*)(src + (i * 4 + cf) * 256 + lane * 4);
#pragma unroll
        for (int i = 0; i < 4; i++)
            lacc[i] += *(const f32x4*)(src + (16 + i) * 256 + lane * 4);

#pragma unroll
        for (int i = 0; i < 4; i++)
#pragma unroll
            for (int r = 0; r < 4; r++) {
                float inv = 1.0f / lacc[i][r];
                int n = qbase + i * 16 + lg * 4 + r;
                size_t obase = ((size_t)b * 1024 + n) * 512 + h * 64;
#pragma unroll
                for (int cf = 0; cf < 4; cf++)
                    aoT[obase + cf * 16 + l15] = f2bf(oacc[i][cf][r] * inv);
            }
    }
}

// ---------------------------------------------------------------- proj GEMM + residual
__global__ __launch_bounds__(256) void gemm_proj(const ushort* __restrict__ Wb,
                                                 const ushort* __restrict__ aoT,
                                                 const float* __restrict__ projb,
                                                 const float* __restrict__ x,
                                                 float* __restrict__ out) {
    int lane = threadIdx.x & 63, wave = threadIdx.x >> 6;
    int l15 = lane & 15, lg = lane >> 4;
    int bi = blockIdx.x;
    int b = bi & 7;
    int slot = bi >> 3;
    int m0 = (slot & 3) * 128;
    int n0 = (slot >> 2) * 64;
    int mw = (wave >> 1) * 64, nw = (wave & 1) * 32;
    const ushort* Ag = Wb + (size_t)m0 * 512;
    const ushort* Bg = aoT + (size_t)b * 524288 + (size_t)n0 * 512;

    __shared__ ushort abuf[4][4096];
    __shared__ ushort bbuf[4][2048];

    f32x4 acc[4][2] = {};
#pragma unroll
    for (int p = 0; p < 3; ++p) {
        stage_tile32(abuf[p], Ag + p * 32, 512, 8, wave, lane);
        stage_tile32(bbuf[p], Bg + p * 32, 512, 4, wave, lane);
    }
    asm volatile("s_waitcnt vmcnt(6)" ::: "memory");
    __builtin_amdgcn_s_barrier();

#pragma unroll 1
    for (int t = 0; t < 16; ++t) {
        if (t < 13) {
            int nxt = (t + 3) & 3;
            stage_tile32(abuf[nxt], Ag + (t + 3) * 32, 512, 8, wave, lane);
            stage_tile32(bbuf[nxt], Bg + (t + 3) * 32, 512, 4, wave, lane);
        }
        const ushort* A = abuf[t & 3];
        const ushort* B = bbuf[t & 3];
        bf16x8 af[4], bfr[2];
#pragma unroll
        for (int i = 0; i < 4; i++)
            af[i] = lds_read_row32(A, mw + i * 16 + l15, lg * 16);
#pragma unroll
        for (int j = 0; j < 2; j++)
            bfr[j] = lds_read_row32(B, nw + j * 16 + l15, lg * 16);
        __builtin_amdgcn_s_setprio(1);
#pragma unroll
        for (int i = 0; i < 4; i++)
#pragma unroll
            for (int j = 0; j < 2; j++)
                acc[i][j] = MFMA(af[i], bfr[j], acc[i][j]);
        __builtin_amdgcn_s_setprio(0);
        if (t < 15) {
            if (t < 13)      asm volatile("s_waitcnt vmcnt(6)" ::: "memory");
            else if (t == 13) asm volatile("s_waitcnt vmcnt(3)" ::: "memory");
            else              asm volatile("s_waitcnt vmcnt(0)" ::: "memory");
            __builtin_amdgcn_s_barrier();
        }
    }

#pragma unroll
    for (int i = 0; i < 4; i++) {
        int ob = m0 + mw + i * 16 + lg * 4;
        float bias[4];
#pragma unroll
        for (int r = 0; r < 4; r++) bias[r] = projb[ob + r];
#pragma unroll
        for (int j = 0; j < 2; j++) {
            int n = n0 + nw + j * 16 + l15;
#pragma unroll
            for (int r = 0; r < 4; r++) {
                size_t idx = (size_t)(b * 512 + ob + r) * 1024 + n;
                out[idx] = x[idx] + bias[r] + acc[i][j][r];
            }
        }
    }
}

// ---------------------------------------------------------------- launcher
extern "C" void kernel_launch(void* const* d_in, const int* in_sizes, int n_in,
                              void* d_out, int out_size, void* d_ws, size_t ws_size,
                              hipStream_t stream) {
    const float* x     = (const float*)d_in[0];
    const float* gnw   = (const float*)d_in[1];
    const float* gnb   = (const float*)d_in[2];
    const float* qkvw  = (const float*)d_in[3];
    const float* qkvb  = (const float*)d_in[4];
    const float* projw = (const float*)d_in[5];
    const float* projb = (const float*)d_in[6];
    float* out = (float*)d_out;

    char* ws = (char*)d_ws;
    ushort* hnT    = (ushort*)(ws);                          // 8 MB (reused as aoT)
    ushort* qT     = (ushort*)(ws + (size_t)(8u << 20));     // 8 MB
    ushort* kT     = (ushort*)(ws + (size_t)(16u << 20));    // 8 MB
    ushort* vbuf   = (ushort*)(ws + (size_t)(24u << 20));    // 8 MB
    ushort* qkvwb  = (ushort*)(ws + (size_t)(32u << 20));    // 1.5 MB
    ushort* projwb = (ushort*)(ws + (size_t)(32u << 20) + 1572864);  // 0.5 MB

    gn_cvt_kernel<<<dim3(1280), dim3(256), 0, stream>>>(x, gnw, gnb, hnT,
                                                        qkvw, projw, qkvwb, projwb);
    gemm_qkv<<<dim3(768), dim3(256), 0, stream>>>(qkvwb, hnT, qkvb, qT, kT, vbuf);
    attn_kernel<<<dim3(512), dim3(256), 0, stream>>>(qT, kT, vbuf, hnT /* aoT */);
    gemm_proj<<<dim3(512), dim3(256), 0, stream>>>(projwb, hnT, projb, x, out);
}

// Round 16
// 79.628 us; speedup vs baseline: 1.1398x; 1.1398x over previous
//
#include <hip/hip_runtime.h>

typedef __bf16 bf16x8 __attribute__((ext_vector_type(8)));
typedef float f32x4 __attribute__((ext_vector_type(4)));

#define MFMA(a, b, c) __builtin_amdgcn_mfma_f32_16x16x32_bf16(a, b, c, 0, 0, 0)

#define CS 0.18033688011112042f   /* 0.125 * log2(e) */

__device__ __forceinline__ ushort f2bf(float f) {
    __bf16 h = (__bf16)f;
    return *(ushort*)&h;
}
__device__ __forceinline__ float bf2f(ushort u) {
    unsigned int x = ((unsigned int)u) << 16;
    return __uint_as_float(x);
}

// ---- stage (8*nchunks)-row x 64-col bf16 tile into LDS, XOR-swizzled (128B rows)
__device__ __forceinline__ void stage_tile64(ushort* lds, const ushort* gbase,
                                             int row_stride, int nchunks,
                                             int wave, int lane) {
    int r8 = lane >> 3;
    int cswz = ((lane & 7) ^ r8) << 4;
#pragma unroll
    for (int c = wave; c < nchunks; c += 4) {
        const char* g = (const char*)(gbase + (size_t)(c * 8 + r8) * row_stride) + cswz;
        __builtin_amdgcn_global_load_lds(
            (const __attribute__((address_space(1))) unsigned int*)g,
            (__attribute__((address_space(3))) unsigned int*)((char*)lds + c * 1024),
            16, 0, 0);
    }
}

__device__ __forceinline__ bf16x8 lds_read_row(const ushort* lds, int row, int cb) {
    return *(const bf16x8*)((const char*)lds + row * 128 + (cb ^ ((row & 7) << 4)));
}

// ---- stage (16*nchunks)-row x 32-col bf16 tile into LDS, XOR-swizzled (64B rows)
__device__ __forceinline__ void stage_tile32(ushort* lds, const ushort* gbase,
                                             int row_stride, int nchunks,
                                             int wave, int lane) {
    int r16 = lane >> 2;
    int csw = (((lane & 3) ^ ((lane >> 3) & 3)) << 3);
#pragma unroll
    for (int c = wave; c < nchunks; c += 4) {
        const ushort* g = gbase + (size_t)(c * 16 + r16) * row_stride + csw;
        __builtin_amdgcn_global_load_lds(
            (const __attribute__((address_space(1))) unsigned int*)g,
            (__attribute__((address_space(3))) unsigned int*)((char*)lds + c * 1024),
            16, 0, 0);
    }
}

__device__ __forceinline__ bf16x8 lds_read_row32(const ushort* lds, int row, int cb) {
    return *(const bf16x8*)((const char*)lds + row * 64 + (cb ^ (((row >> 1) & 3) << 4)));
}

// ---------------------------------------------------------------- groupnorm (+fused weight cvt)
// blocks [0,256): GroupNorm per (b,g) -- x read ONCE from HBM (stats + bf16
// tile cache in LDS in pass 1; normalize from LDS in pass 2).
// blocks [256,1280): fp32->bf16 weight cvt.
__global__ __launch_bounds__(256) void gn_cvt_kernel(const float* __restrict__ x,
                                                     const float* __restrict__ gnw,
                                                     const float* __restrict__ gnb,
                                                     ushort* __restrict__ hnT,
                                                     const float* __restrict__ w1,
                                                     const float* __restrict__ w2,
                                                     ushort* __restrict__ o1,
                                                     ushort* __restrict__ o2) {
    __shared__ ushort xcache[16 * 1028];   // ~32.1 KB
    __shared__ float red[8];
    __shared__ float sw[16], sb[16];

    if (blockIdx.x >= 256) {
        int t = (blockIdx.x - 256) * 256 + threadIdx.x;
        const int n1q = (1536 * 512) / 4;
        float4 v;
        ushort* dst;
        int idx;
        if (t < n1q) {
            v = ((const float4*)w1)[t]; dst = o1; idx = t;
        } else {
            idx = t - n1q;
            v = ((const float4*)w2)[idx]; dst = o2;
        }
        ushort4 p;
        p.x = f2bf(v.x); p.y = f2bf(v.y); p.z = f2bf(v.z); p.w = f2bf(v.w);
        ((ushort4*)dst)[idx] = p;
        return;
    }

    int b = blockIdx.x >> 5, g = blockIdx.x & 31;
    const float* xp = x + (size_t)(b * 512 + g * 16) * 1024;
    int t = threadIdx.x;

    float s = 0.f, ss = 0.f;
    const float4* xp4 = (const float4*)xp;
    for (int i = t; i < 4096; i += 256) {
        float4 v = xp4[i];
        s += (v.x + v.y) + (v.z + v.w);
        ss += (v.x * v.x + v.y * v.y) + (v.z * v.z + v.w * v.w);
        int f = i * 4;
        int cc = f >> 10, nl = f & 1023;
        ushort4 c;
        c.x = f2bf(v.x); c.y = f2bf(v.y); c.z = f2bf(v.z); c.w = f2bf(v.w);
        *(ushort4*)&xcache[cc * 1028 + nl] = c;
    }
#pragma unroll
    for (int off = 32; off >= 1; off >>= 1) {
        s += __shfl_xor(s, off);
        ss += __shfl_xor(ss, off);
    }
    int wave = t >> 6;
    if ((t & 63) == 0) { red[wave] = s; red[wave + 4] = ss; }
    if (t < 16) { sw[t] = gnw[g * 16 + t]; sb[t] = gnb[g * 16 + t]; }
    __syncthreads();
    float S = red[0] + red[1] + red[2] + red[3];
    float SS = red[4] + red[5] + red[6] + red[7];
    float mean = S * (1.0f / 16384.0f);
    float var = SS * (1.0f / 16384.0f) - mean * mean;
    float rstd = rsqrtf(var + 1e-5f);

    int cc0 = (t & 3) * 4;
    int nb = t >> 2;
    float w0 = sw[cc0] * rstd, w1_ = sw[cc0 + 1] * rstd,
          w2_ = sw[cc0 + 2] * rstd, w3 = sw[cc0 + 3] * rstd;
    float b0 = sb[cc0] - mean * w0, b1 = sb[cc0 + 1] - mean * w1_,
          b2 = sb[cc0 + 2] - mean * w2_, b3 = sb[cc0 + 3] - mean * w3;
#pragma unroll
    for (int k = 0; k < 16; ++k) {
        int nl = nb + 64 * k;
        ushort4 p;
        p.x = f2bf(bf2f(xcache[(cc0 + 0) * 1028 + nl]) * w0 + b0);
        p.y = f2bf(bf2f(xcache[(cc0 + 1) * 1028 + nl]) * w1_ + b1);
        p.z = f2bf(bf2f(xcache[(cc0 + 2) * 1028 + nl]) * w2_ + b2);
        p.w = f2bf(bf2f(xcache[(cc0 + 3) * 1028 + nl]) * w3 + b3);
        *(ushort4*)(hnT + ((size_t)b * 1024 + nl) * 512 + g * 16 + cc0) = p;
    }
}

// ---------------------------------------------------------------- QKV GEMM
// BK=32, triple-buffered ring (48KB -> 3 blocks/CU), counted-vmcnt pipeline.
// V written kv-permuted (pi^-1) for attention's in-register P; Q pre-scaled.
__global__ __launch_bounds__(256, 3) void gemm_qkv(const ushort* __restrict__ Wb,
                                                   const ushort* __restrict__ hnT,
                                                   const float* __restrict__ qkvb,
                                                   ushort* __restrict__ qT,
                                                   ushort* __restrict__ kT,
                                                   ushort* __restrict__ vb) {
    int lane = threadIdx.x & 63, wave = threadIdx.x >> 6;
    int l15 = lane & 15, lg = lane >> 4;
    int bi = blockIdx.x;
    int b = bi & 7;
    int slot = bi >> 3;
    int m0 = (slot % 12) * 128;
    int n0 = (slot / 12) * 128;
    int mw = (wave >> 1) * 64, nw = (wave & 1) * 64;
    const ushort* Ag = Wb + (size_t)m0 * 512;
    const ushort* Bg = hnT + (size_t)b * 524288 + (size_t)n0 * 512;

    __shared__ ushort abuf[3][4096];
    __shared__ ushort bbuf[3][4096];

    f32x4 acc[4][4] = {};
#pragma unroll
    for (int p = 0; p < 2; ++p) {
        stage_tile32(abuf[p], Ag + p * 32, 512, 8, wave, lane);
        stage_tile32(bbuf[p], Bg + p * 32, 512, 8, wave, lane);
    }
    asm volatile("s_waitcnt vmcnt(4)" ::: "memory");
    __builtin_amdgcn_s_barrier();

    int cur = 0;
#pragma unroll 1
    for (int t = 0; t < 16; ++t) {
        if (t < 14) {
            int nxt = cur + 2; if (nxt >= 3) nxt -= 3;
            stage_tile32(abuf[nxt], Ag + (t + 2) * 32, 512, 8, wave, lane);
            stage_tile32(bbuf[nxt], Bg + (t + 2) * 32, 512, 8, wave, lane);
        }
        const ushort* A = abuf[cur];
        const ushort* B = bbuf[cur];
        bf16x8 af[4], bfr[4];
#pragma unroll
        for (int i = 0; i < 4; i++)
            af[i] = lds_read_row32(A, mw + i * 16 + l15, lg * 16);
#pragma unroll
        for (int j = 0; j < 4; j++)
            bfr[j] = lds_read_row32(B, nw + j * 16 + l15, lg * 16);
        __builtin_amdgcn_s_setprio(1);
#pragma unroll
        for (int i = 0; i < 4; i++)
#pragma unroll
            for (int j = 0; j < 4; j++)
                acc[i][j] = MFMA(af[i], bfr[j], acc[i][j]);
        __builtin_amdgcn_s_setprio(0);
        if (t < 15) {
            if (t < 14) asm volatile("s_waitcnt vmcnt(4)" ::: "memory");
            else        asm volatile("s_waitcnt vmcnt(0)" ::: "memory");
            __builtin_amdgcn_s_barrier();
        }
        cur = cur + 1; if (cur == 3) cur = 0;
    }

#pragma unroll
    for (int i = 0; i < 4; i++) {
        int ob = m0 + mw + i * 16 + lg * 4;
        float bias[4];
#pragma unroll
        for (int r = 0; r < 4; r++) bias[r] = qkvb[ob + r];
        int part = ob >> 9;
        int oo = ob & 511;
#pragma unroll
        for (int j = 0; j < 4; j++) {
            int n = n0 + nw + j * 16 + l15;
            if (part == 2) {
                int L = n & 63;
                int cf = L >> 4;
                int s = ((cf >> 1) << 5) | (((L >> 2) & 3) << 3) | ((cf & 1) << 2) | (L & 3);
                int np = (n & ~63) | s;
#pragma unroll
                for (int r = 0; r < 4; r++)
                    vb[(size_t)(b * 512 + oo + r) * 1024 + np] = f2bf(acc[i][j][r] + bias[r]);
            } else {
                ushort* dst = part ? kT : qT;
                float sc = part ? 1.0f : CS;
                int h = oo >> 6, dd = oo & 63;
                ushort4 p;
                p.x = f2bf((acc[i][j][0] + bias[0]) * sc);
                p.y = f2bf((acc[i][j][1] + bias[1]) * sc);
                p.z = f2bf((acc[i][j][2] + bias[2]) * sc);
                p.w = f2bf((acc[i][j][3] + bias[3]) * sc);
                *(ushort4*)(dst + ((size_t)((b * 8 + h) * 1024 + n)) * 64 + dd) = p;
            }
        }
    }
}

// ---------------------------------------------------------------- attention
// 128 q-rows/block (4 waves x 32 rows). K/V on a 4-buffer ring, TWO kv-tiles
// per barrier group: stage group g+1 (8 loads/wave) at group top, compute
// both tiles back-to-back, vmcnt(0)+barrier once per group (7 barriers vs 15;
// prefetch cover = full 2-tile compute). Swapped QK^T keeps P in registers
// (V kv-permuted by pi^-1 in gemm_qkv). Q pre-scaled: P = exp2(S). Row sums
// via ones-MFMA.
__global__ __launch_bounds__(256) void attn_kernel(const ushort* __restrict__ qT,
                                                   const ushort* __restrict__ kT,
                                                   const ushort* __restrict__ vb,
                                                   ushort* __restrict__ aoT) {
    int bi = blockIdx.x;
    int bh = ((bi >> 6) << 3) | (bi & 7);
    int q0 = ((bi >> 3) & 7) * 128;
    int b = bh >> 3, h = bh & 7;
    int lane = threadIdx.x & 63, wave = threadIdx.x >> 6;
    int l15 = lane & 15, lg = lane >> 4;
    const ushort* qp = qT + (size_t)bh * 65536;
    const ushort* kp = kT + (size_t)bh * 65536;
    const ushort* vp = vb + (size_t)bh * 65536;

    __shared__ ushort kbuf[4][4096];   // [kv 64][d 64]
    __shared__ ushort vbuf[4][4096];   // [dd 64][kv-slot 64] (pi-permuted)

    bf16x8 vone;
#pragma unroll
    for (int e = 0; e < 8; e++) vone[e] = (__bf16)1.0f;

    bf16x8 qf[2][2];
#pragma unroll
    for (int i = 0; i < 2; i++)
#pragma unroll
        for (int kh = 0; kh < 2; kh++)
            qf[i][kh] = *(const bf16x8*)(qp + (size_t)(q0 + wave * 32 + i * 16 + l15) * 64 + kh * 32 + lg * 8);

    f32x4 oacc[2][4] = {};
    f32x4 lacc[2] = {};

    // prologue: stage group 0 (tiles 0,1)
    stage_tile64(kbuf[0], kp, 64, 8, wave, lane);
    stage_tile64(vbuf[0], vp, 1024, 8, wave, lane);
    stage_tile64(kbuf[1], kp + 4096, 64, 8, wave, lane);
    stage_tile64(vbuf[1], vp + 64, 1024, 8, wave, lane);
    asm volatile("s_waitcnt vmcnt(0)" ::: "memory");
    __builtin_amdgcn_s_barrier();

#pragma unroll 1
    for (int g = 0; g < 8; ++g) {
        int t0 = 2 * g;
        if (g < 7) {
            int na = (t0 + 2) & 3, nb2 = (t0 + 3) & 3;
            stage_tile64(kbuf[na], kp + (size_t)(t0 + 2) * 4096, 64, 8, wave, lane);
            stage_tile64(vbuf[na], vp + (t0 + 2) * 64, 1024, 8, wave, lane);
            stage_tile64(kbuf[nb2], kp + (size_t)(t0 + 3) * 4096, 64, 8, wave, lane);
            stage_tile64(vbuf[nb2], vp + (t0 + 3) * 64, 1024, 8, wave, lane);
        }
#pragma unroll
        for (int u = 0; u < 2; ++u) {
            int t = t0 + u;
            const ushort* kb = kbuf[t & 3];
            const ushort* vc = vbuf[t & 3];

            f32x4 sacc[2][4] = {};
            __builtin_amdgcn_s_setprio(1);
#pragma unroll
            for (int kh = 0; kh < 2; kh++)
#pragma unroll
                for (int cf = 0; cf < 4; cf++) {
                    bf16x8 kf = lds_read_row(kb, cf * 16 + l15, kh * 64 + lg * 16);
                    sacc[0][cf] = MFMA(kf, qf[0][kh], sacc[0][cf]);
                    sacc[1][cf] = MFMA(kf, qf[1][kh], sacc[1][cf]);
                }
            __builtin_amdgcn_s_setprio(0);

            bf16x8 vf[2][4];
#pragma unroll
            for (int ks = 0; ks < 2; ks++)
#pragma unroll
                for (int cf = 0; cf < 4; cf++)
                    vf[ks][cf] = lds_read_row(vc, cf * 16 + l15, ks * 64 + lg * 16);

            bf16x8 pa[2][2];
#pragma unroll
            for (int i = 0; i < 2; i++)
#pragma unroll
                for (int ks = 0; ks < 2; ks++) {
                    bf16x8 tr;
#pragma unroll
                    for (int jhi = 0; jhi < 2; jhi++)
#pragma unroll
                        for (int r = 0; r < 4; r++)
                            tr[jhi * 4 + r] = (__bf16)exp2f(sacc[i][ks * 2 + jhi][r]);
                    pa[i][ks] = tr;
                }

            __builtin_amdgcn_s_setprio(1);
#pragma unroll
            for (int i = 0; i < 2; i++)
#pragma unroll
                for (int ks = 0; ks < 2; ks++) {
                    lacc[i] = MFMA(pa[i][ks], vone, lacc[i]);
#pragma unroll
                    for (int cf = 0; cf < 4; cf++)
                        oacc[i][cf] = MFMA(pa[i][ks], vf[ks][cf], oacc[i][cf]);
                }
            __builtin_amdgcn_s_setprio(0);
        }
        if (g < 7) {
            asm volatile("s_waitcnt vmcnt(0)" ::: "memory");
            __builtin_amdgcn_s_barrier();
        }
    }

#pragma unroll
    for (int i = 0; i < 2; i++)
#pragma unroll
        for (int r = 0; r < 4; r++) {
            float inv = 1.0f / lacc[i][r];
            int n = q0 + wave * 32 + i * 16 + lg * 4 + r;
            size_t obase = ((size_t)b * 1024 + n) * 512 + h * 64;
#pragma unroll
            for (int cf = 0; cf < 4; cf++)
                aoT[obase + cf * 16 + l15] = f2bf(oacc[i][cf][r] * inv);
        }
}

// ---------------------------------------------------------------- proj GEMM + residual
__global__ __launch_bounds__(256) void gemm_proj(const ushort* __restrict__ Wb,
                                                 const ushort* __restrict__ aoT,
                                                 const float* __restrict__ projb,
                                                 const float* __restrict__ x,
                                                 float* __restrict__ out) {
    int lane = threadIdx.x & 63, wave = threadIdx.x >> 6;
    int l15 = lane & 15, lg = lane >> 4;
    int bi = blockIdx.x;
    int b = bi & 7;
    int slot = bi >> 3;
    int m0 = (slot & 3) * 128;
    int n0 = (slot >> 2) * 64;
    int mw = (wave >> 1) * 64, nw = (wave & 1) * 32;
    const ushort* Ag = Wb + (size_t)m0 * 512;
    const ushort* Bg = aoT + (size_t)b * 524288 + (size_t)n0 * 512;

    __shared__ ushort abuf[4][4096];
    __shared__ ushort bbuf[4][2048];

    f32x4 acc[4][2] = {};
#pragma unroll
    for (int p = 0; p < 3; ++p) {
        stage_tile32(abuf[p], Ag + p * 32, 512, 8, wave, lane);
        stage_tile32(bbuf[p], Bg + p * 32, 512, 4, wave, lane);
    }
    asm volatile("s_waitcnt vmcnt(6)" ::: "memory");
    __builtin_amdgcn_s_barrier();

#pragma unroll 1
    for (int t = 0; t < 16; ++t) {
        if (t < 13) {
            int nxt = (t + 3) & 3;
            stage_tile32(abuf[nxt], Ag + (t + 3) * 32, 512, 8, wave, lane);
            stage_tile32(bbuf[nxt], Bg + (t + 3) * 32, 512, 4, wave, lane);
        }
        const ushort* A = abuf[t & 3];
        const ushort* B = bbuf[t & 3];
        bf16x8 af[4], bfr[2];
#pragma unroll
        for (int i = 0; i < 4; i++)
            af[i] = lds_read_row32(A, mw + i * 16 + l15, lg * 16);
#pragma unroll
        for (int j = 0; j < 2; j++)
            bfr[j] = lds_read_row32(B, nw + j * 16 + l15, lg * 16);
        __builtin_amdgcn_s_setprio(1);
#pragma unroll
        for (int i = 0; i < 4; i++)
#pragma unroll
            for (int j = 0; j < 2; j++)
                acc[i][j] = MFMA(af[i], bfr[j], acc[i][j]);
        __builtin_amdgcn_s_setprio(0);
        if (t < 15) {
            if (t < 13)      asm volatile("s_waitcnt vmcnt(6)" ::: "memory");
            else if (t == 13) asm volatile("s_waitcnt vmcnt(3)" ::: "memory");
            else              asm volatile("s_waitcnt vmcnt(0)" ::: "memory");
            __builtin_amdgcn_s_barrier();
        }
    }

#pragma unroll
    for (int i = 0; i < 4; i++) {
        int ob = m0 + mw + i * 16 + lg * 4;
        float bias[4];
#pragma unroll
        for (int r = 0; r < 4; r++) bias[r] = projb[ob + r];
#pragma unroll
        for (int j = 0; j < 2; j++) {
            int n = n0 + nw + j * 16 + l15;
#pragma unroll
            for (int r = 0; r < 4; r++) {
                size_t idx = (size_t)(b * 512 + ob + r) * 1024 + n;
                out[idx] = x[idx] + bias[r] + acc[i][j][r];
            }
        }
    }
}

// ---------------------------------------------------------------- launcher
extern "C" void kernel_launch(void* const* d_in, const int* in_sizes, int n_in,
                              void* d_out, int out_size, void* d_ws, size_t ws_size,
                              hipStream_t stream) {
    const float* x     = (const float*)d_in[0];
    const float* gnw   = (const float*)d_in[1];
    const float* gnb   = (const float*)d_in[2];
    const float* qkvw  = (const float*)d_in[3];
    const float* qkvb  = (const float*)d_in[4];
    const float* projw = (const float*)d_in[5];
    const float* projb = (const float*)d_in[6];
    float* out = (float*)d_out;

    char* ws = (char*)d_ws;
    ushort* hnT    = (ushort*)(ws);                          // 8 MB (reused as aoT)
    ushort* qT     = (ushort*)(ws + (size_t)(8u << 20));     // 8 MB
    ushort* kT     = (ushort*)(ws + (size_t)(16u << 20));    // 8 MB
    ushort* vbuf   = (ushort*)(ws + (size_t)(24u << 20));    // 8 MB
    ushort* qkvwb  = (ushort*)(ws + (size_t)(32u << 20));    // 1.5 MB
    ushort* projwb = (ushort*)(ws + (size_t)(32u << 20) + 1572864);  // 0.5 MB

    gn_cvt_kernel<<<dim3(1280), dim3(256), 0, stream>>>(x, gnw, gnb, hnT,
                                                        qkvw, projw, qkvwb, projwb);
    gemm_qkv<<<dim3(768), dim3(256), 0, stream>>>(qkvwb, hnT, qkvb, qT, kT, vbuf);
    attn_kernel<<<dim3(512), dim3(256), 0, stream>>>(qT, kT, vbuf, hnT /* aoT */);
    gemm_proj<<<dim3(512), dim3(256), 0, stream>>>(projwb, hnT, projb, x, out);
}

// Round 17
// 76.516 us; speedup vs baseline: 1.1862x; 1.0407x over previous
//
#include <hip/hip_runtime.h>

typedef __bf16 bf16x8 __attribute__((ext_vector_type(8)));
typedef float f32x4 __attribute__((ext_vector_type(4)));

#define MFMA(a, b, c) __builtin_amdgcn_mfma_f32_16x16x32_bf16(a, b, c, 0, 0, 0)

#define CS 0.18033688011112042f   /* 0.125 * log2(e) */

__device__ __forceinline__ ushort f2bf(float f) {
    __bf16 h = (__bf16)f;
    return *(ushort*)&h;
}
__device__ __forceinline__ float bf2f(ushort u) {
    unsigned int x = ((unsigned int)u) << 16;
    return __uint_as_float(x);
}

// ---- stage (8*nchunks)-row x 64-col bf16 tile into LDS, XOR-swizzled (128B rows)
__device__ __forceinline__ void stage_tile64(ushort* lds, const ushort* gbase,
                                             int row_stride, int nchunks,
                                             int wave, int lane) {
    int r8 = lane >> 3;
    int cswz = ((lane & 7) ^ r8) << 4;
#pragma unroll
    for (int c = wave; c < nchunks; c += 4) {
        const char* g = (const char*)(gbase + (size_t)(c * 8 + r8) * row_stride) + cswz;
        __builtin_amdgcn_global_load_lds(
            (const __attribute__((address_space(1))) unsigned int*)g,
            (__attribute__((address_space(3))) unsigned int*)((char*)lds + c * 1024),
            16, 0, 0);
    }
}

__device__ __forceinline__ bf16x8 lds_read_row(const ushort* lds, int row, int cb) {
    return *(const bf16x8*)((const char*)lds + row * 128 + (cb ^ ((row & 7) << 4)));
}

// ---- stage (16*nchunks)-row x 32-col bf16 tile into LDS, XOR-swizzled (64B rows)
__device__ __forceinline__ void stage_tile32(ushort* lds, const ushort* gbase,
                                             int row_stride, int nchunks,
                                             int wave, int lane) {
    int r16 = lane >> 2;
    int csw = (((lane & 3) ^ ((lane >> 3) & 3)) << 3);
#pragma unroll
    for (int c = wave; c < nchunks; c += 4) {
        const ushort* g = gbase + (size_t)(c * 16 + r16) * row_stride + csw;
        __builtin_amdgcn_global_load_lds(
            (const __attribute__((address_space(1))) unsigned int*)g,
            (__attribute__((address_space(3))) unsigned int*)((char*)lds + c * 1024),
            16, 0, 0);
    }
}

__device__ __forceinline__ bf16x8 lds_read_row32(const ushort* lds, int row, int cb) {
    return *(const bf16x8*)((const char*)lds + row * 64 + (cb ^ (((row >> 1) & 3) << 4)));
}

// ---------------------------------------------------------------- groupnorm (+fused weight cvt)
// 512-thread blocks: 8 waves/CU during the latency-bound 64KB fp32 read phase
// (was 4). blocks [0,256): GroupNorm per (b,g), x read ONCE (stats + bf16 tile
// cache in LDS pass 1; normalize from LDS pass 2). blocks [256,768): weight cvt.
__global__ __launch_bounds__(512) void gn_cvt_kernel(const float* __restrict__ x,
                                                     const float* __restrict__ gnw,
                                                     const float* __restrict__ gnb,
                                                     ushort* __restrict__ hnT,
                                                     const float* __restrict__ w1,
                                                     const float* __restrict__ w2,
                                                     ushort* __restrict__ o1,
                                                     ushort* __restrict__ o2) {
    __shared__ ushort xcache[16 * 1028];   // ~32.1 KB
    __shared__ float red[16];
    __shared__ float sw[16], sb[16];

    if (blockIdx.x >= 256) {
        int t = (blockIdx.x - 256) * 512 + threadIdx.x;   // 0..262143
        const int n1q = (1536 * 512) / 4;
        float4 v;
        ushort* dst;
        int idx;
        if (t < n1q) {
            v = ((const float4*)w1)[t]; dst = o1; idx = t;
        } else {
            idx = t - n1q;
            v = ((const float4*)w2)[idx]; dst = o2;
        }
        ushort4 p;
        p.x = f2bf(v.x); p.y = f2bf(v.y); p.z = f2bf(v.z); p.w = f2bf(v.w);
        ((ushort4*)dst)[idx] = p;
        return;
    }

    int b = blockIdx.x >> 5, g = blockIdx.x & 31;
    const float* xp = x + (size_t)(b * 512 + g * 16) * 1024;
    int t = threadIdx.x;

    float s = 0.f, ss = 0.f;
    const float4* xp4 = (const float4*)xp;
    for (int i = t; i < 4096; i += 512) {
        float4 v = xp4[i];
        s += (v.x + v.y) + (v.z + v.w);
        ss += (v.x * v.x + v.y * v.y) + (v.z * v.z + v.w * v.w);
        int f = i * 4;
        int cc = f >> 10, nl = f & 1023;
        ushort4 c;
        c.x = f2bf(v.x); c.y = f2bf(v.y); c.z = f2bf(v.z); c.w = f2bf(v.w);
        *(ushort4*)&xcache[cc * 1028 + nl] = c;
    }
#pragma unroll
    for (int off = 32; off >= 1; off >>= 1) {
        s += __shfl_xor(s, off);
        ss += __shfl_xor(ss, off);
    }
    int wave = t >> 6;
    if ((t & 63) == 0) { red[wave] = s; red[wave + 8] = ss; }
    if (t < 16) { sw[t] = gnw[g * 16 + t]; sb[t] = gnb[g * 16 + t]; }
    __syncthreads();
    float S = red[0] + red[1] + red[2] + red[3] + red[4] + red[5] + red[6] + red[7];
    float SS = red[8] + red[9] + red[10] + red[11] + red[12] + red[13] + red[14] + red[15];
    float mean = S * (1.0f / 16384.0f);
    float var = SS * (1.0f / 16384.0f) - mean * mean;
    float rstd = rsqrtf(var + 1e-5f);

    int cc0 = (t & 3) * 4;
    int nb = t >> 2;                        // 0..127
    float w0 = sw[cc0] * rstd, w1_ = sw[cc0 + 1] * rstd,
          w2_ = sw[cc0 + 2] * rstd, w3 = sw[cc0 + 3] * rstd;
    float b0 = sb[cc0] - mean * w0, b1 = sb[cc0 + 1] - mean * w1_,
          b2 = sb[cc0 + 2] - mean * w2_, b3 = sb[cc0 + 3] - mean * w3;
#pragma unroll
    for (int k = 0; k < 8; ++k) {
        int nl = nb + 128 * k;
        ushort4 p;
        p.x = f2bf(bf2f(xcache[(cc0 + 0) * 1028 + nl]) * w0 + b0);
        p.y = f2bf(bf2f(xcache[(cc0 + 1) * 1028 + nl]) * w1_ + b1);
        p.z = f2bf(bf2f(xcache[(cc0 + 2) * 1028 + nl]) * w2_ + b2);
        p.w = f2bf(bf2f(xcache[(cc0 + 3) * 1028 + nl]) * w3 + b3);
        *(ushort4*)(hnT + ((size_t)b * 1024 + nl) * 512 + g * 16 + cc0) = p;
    }
}

// ---------------------------------------------------------------- QKV GEMM
// BK=32, triple-buffered ring (48KB -> 3 blocks/CU), counted-vmcnt pipeline.
// V written kv-permuted (pi^-1) for attention's in-register P; Q pre-scaled.
__global__ __launch_bounds__(256, 3) void gemm_qkv(const ushort* __restrict__ Wb,
                                                   const ushort* __restrict__ hnT,
                                                   const float* __restrict__ qkvb,
                                                   ushort* __restrict__ qT,
                                                   ushort* __restrict__ kT,
                                                   ushort* __restrict__ vb) {
    int lane = threadIdx.x & 63, wave = threadIdx.x >> 6;
    int l15 = lane & 15, lg = lane >> 4;
    int bi = blockIdx.x;
    int b = bi & 7;
    int slot = bi >> 3;
    int m0 = (slot % 12) * 128;
    int n0 = (slot / 12) * 128;
    int mw = (wave >> 1) * 64, nw = (wave & 1) * 64;
    const ushort* Ag = Wb + (size_t)m0 * 512;
    const ushort* Bg = hnT + (size_t)b * 524288 + (size_t)n0 * 512;

    __shared__ ushort abuf[3][4096];
    __shared__ ushort bbuf[3][4096];

    f32x4 acc[4][4] = {};
#pragma unroll
    for (int p = 0; p < 2; ++p) {
        stage_tile32(abuf[p], Ag + p * 32, 512, 8, wave, lane);
        stage_tile32(bbuf[p], Bg + p * 32, 512, 8, wave, lane);
    }
    asm volatile("s_waitcnt vmcnt(4)" ::: "memory");
    __builtin_amdgcn_s_barrier();

    int cur = 0;
#pragma unroll 1
    for (int t = 0; t < 16; ++t) {
        if (t < 14) {
            int nxt = cur + 2; if (nxt >= 3) nxt -= 3;
            stage_tile32(abuf[nxt], Ag + (t + 2) * 32, 512, 8, wave, lane);
            stage_tile32(bbuf[nxt], Bg + (t + 2) * 32, 512, 8, wave, lane);
        }
        const ushort* A = abuf[cur];
        const ushort* B = bbuf[cur];
        bf16x8 af[4], bfr[4];
#pragma unroll
        for (int i = 0; i < 4; i++)
            af[i] = lds_read_row32(A, mw + i * 16 + l15, lg * 16);
#pragma unroll
        for (int j = 0; j < 4; j++)
            bfr[j] = lds_read_row32(B, nw + j * 16 + l15, lg * 16);
        __builtin_amdgcn_s_setprio(1);
#pragma unroll
        for (int i = 0; i < 4; i++)
#pragma unroll
            for (int j = 0; j < 4; j++)
                acc[i][j] = MFMA(af[i], bfr[j], acc[i][j]);
        __builtin_amdgcn_s_setprio(0);
        if (t < 15) {
            if (t < 14) asm volatile("s_waitcnt vmcnt(4)" ::: "memory");
            else        asm volatile("s_waitcnt vmcnt(0)" ::: "memory");
            __builtin_amdgcn_s_barrier();
        }
        cur = cur + 1; if (cur == 3) cur = 0;
    }

#pragma unroll
    for (int i = 0; i < 4; i++) {
        int ob = m0 + mw + i * 16 + lg * 4;
        float bias[4];
#pragma unroll
        for (int r = 0; r < 4; r++) bias[r] = qkvb[ob + r];
        int part = ob >> 9;
        int oo = ob & 511;
#pragma unroll
        for (int j = 0; j < 4; j++) {
            int n = n0 + nw + j * 16 + l15;
            if (part == 2) {
                int L = n & 63;
                int cf = L >> 4;
                int s = ((cf >> 1) << 5) | (((L >> 2) & 3) << 3) | ((cf & 1) << 2) | (L & 3);
                int np = (n & ~63) | s;
#pragma unroll
                for (int r = 0; r < 4; r++)
                    vb[(size_t)(b * 512 + oo + r) * 1024 + np] = f2bf(acc[i][j][r] + bias[r]);
            } else {
                ushort* dst = part ? kT : qT;
                float sc = part ? 1.0f : CS;
                int h = oo >> 6, dd = oo & 63;
                ushort4 p;
                p.x = f2bf((acc[i][j][0] + bias[0]) * sc);
                p.y = f2bf((acc[i][j][1] + bias[1]) * sc);
                p.z = f2bf((acc[i][j][2] + bias[2]) * sc);
                p.w = f2bf((acc[i][j][3] + bias[3]) * sc);
                *(ushort4*)(dst + ((size_t)((b * 8 + h) * 1024 + n)) * 64 + dd) = p;
            }
        }
    }
}

// ---------------------------------------------------------------- attention
// 128 q-rows/block (4 waves x 32 rows). K/V on a 4-buffer ring, TWO kv-tiles
// per barrier group: stage group g+1 (8 loads/wave) at group top, compute
// both tiles back-to-back, vmcnt(0)+barrier once per group. Swapped QK^T
// keeps P in registers (V kv-permuted by pi^-1 in gemm_qkv). Q pre-scaled:
// P = exp2(S). Row sums via ones-MFMA.  [FROZEN: best-measured structure]
__global__ __launch_bounds__(256) void attn_kernel(const ushort* __restrict__ qT,
                                                   const ushort* __restrict__ kT,
                                                   const ushort* __restrict__ vb,
                                                   ushort* __restrict__ aoT) {
    int bi = blockIdx.x;
    int bh = ((bi >> 6) << 3) | (bi & 7);
    int q0 = ((bi >> 3) & 7) * 128;
    int b = bh >> 3, h = bh & 7;
    int lane = threadIdx.x & 63, wave = threadIdx.x >> 6;
    int l15 = lane & 15, lg = lane >> 4;
    const ushort* qp = qT + (size_t)bh * 65536;
    const ushort* kp = kT + (size_t)bh * 65536;
    const ushort* vp = vb + (size_t)bh * 65536;

    __shared__ ushort kbuf[4][4096];   // [kv 64][d 64]
    __shared__ ushort vbuf[4][4096];   // [dd 64][kv-slot 64] (pi-permuted)

    bf16x8 vone;
#pragma unroll
    for (int e = 0; e < 8; e++) vone[e] = (__bf16)1.0f;

    bf16x8 qf[2][2];
#pragma unroll
    for (int i = 0; i < 2; i++)
#pragma unroll
        for (int kh = 0; kh < 2; kh++)
            qf[i][kh] = *(const bf16x8*)(qp + (size_t)(q0 + wave * 32 + i * 16 + l15) * 64 + kh * 32 + lg * 8);

    f32x4 oacc[2][4] = {};
    f32x4 lacc[2] = {};

    stage_tile64(kbuf[0], kp, 64, 8, wave, lane);
    stage_tile64(vbuf[0], vp, 1024, 8, wave, lane);
    stage_tile64(kbuf[1], kp + 4096, 64, 8, wave, lane);
    stage_tile64(vbuf[1], vp + 64, 1024, 8, wave, lane);
    asm volatile("s_waitcnt vmcnt(0)" ::: "memory");
    __builtin_amdgcn_s_barrier();

#pragma unroll 1
    for (int g = 0; g < 8; ++g) {
        int t0 = 2 * g;
        if (g < 7) {
            int na = (t0 + 2) & 3, nb2 = (t0 + 3) & 3;
            stage_tile64(kbuf[na], kp + (size_t)(t0 + 2) * 4096, 64, 8, wave, lane);
            stage_tile64(vbuf[na], vp + (t0 + 2) * 64, 1024, 8, wave, lane);
            stage_tile64(kbuf[nb2], kp + (size_t)(t0 + 3) * 4096, 64, 8, wave, lane);
            stage_tile64(vbuf[nb2], vp + (t0 + 3) * 64, 1024, 8, wave, lane);
        }
#pragma unroll
        for (int u = 0; u < 2; ++u) {
            int t = t0 + u;
            const ushort* kb = kbuf[t & 3];
            const ushort* vc = vbuf[t & 3];

            f32x4 sacc[2][4] = {};
            __builtin_amdgcn_s_setprio(1);
#pragma unroll
            for (int kh = 0; kh < 2; kh++)
#pragma unroll
                for (int cf = 0; cf < 4; cf++) {
                    bf16x8 kf = lds_read_row(kb, cf * 16 + l15, kh * 64 + lg * 16);
                    sacc[0][cf] = MFMA(kf, qf[0][kh], sacc[0][cf]);
                    sacc[1][cf] = MFMA(kf, qf[1][kh], sacc[1][cf]);
                }
            __builtin_amdgcn_s_setprio(0);

            bf16x8 vf[2][4];
#pragma unroll
            for (int ks = 0; ks < 2; ks++)
#pragma unroll
                for (int cf = 0; cf < 4; cf++)
                    vf[ks][cf] = lds_read_row(vc, cf * 16 + l15, ks * 64 + lg * 16);

            bf16x8 pa[2][2];
#pragma unroll
            for (int i = 0; i < 2; i++)
#pragma unroll
                for (int ks = 0; ks < 2; ks++) {
                    bf16x8 tr;
#pragma unroll
                    for (int jhi = 0; jhi < 2; jhi++)
#pragma unroll
                        for (int r = 0; r < 4; r++)
                            tr[jhi * 4 + r] = (__bf16)exp2f(sacc[i][ks * 2 + jhi][r]);
                    pa[i][ks] = tr;
                }

            __builtin_amdgcn_s_setprio(1);
#pragma unroll
            for (int i = 0; i < 2; i++)
#pragma unroll
                for (int ks = 0; ks < 2; ks++) {
                    lacc[i] = MFMA(pa[i][ks], vone, lacc[i]);
#pragma unroll
                    for (int cf = 0; cf < 4; cf++)
                        oacc[i][cf] = MFMA(pa[i][ks], vf[ks][cf], oacc[i][cf]);
                }
            __builtin_amdgcn_s_setprio(0);
        }
        if (g < 7) {
            asm volatile("s_waitcnt vmcnt(0)" ::: "memory");
            __builtin_amdgcn_s_barrier();
        }
    }

#pragma unroll
    for (int i = 0; i < 2; i++)
#pragma unroll
        for (int r = 0; r < 4; r++) {
            float inv = 1.0f / lacc[i][r];
            int n = q0 + wave * 32 + i * 16 + lg * 4 + r;
            size_t obase = ((size_t)b * 1024 + n) * 512 + h * 64;
#pragma unroll
            for (int cf = 0; cf < 4; cf++)
                aoT[obase + cf * 16 + l15] = f2bf(oacc[i][cf][r] * inv);
        }
}

// ---------------------------------------------------------------- proj GEMM + residual
// 64x64 tiles -> grid 1024 = 4 blocks/CU (was 512 = 2/CU, grid-capped).
// 4 waves x 32x32/wave, BK=32, quad ring, counted-vmcnt (2 loads/wave/tile
// -> vmcnt(4) steady). LDS 32KB.
__global__ __launch_bounds__(256) void gemm_proj(const ushort* __restrict__ Wb,
                                                 const ushort* __restrict__ aoT,
                                                 const float* __restrict__ projb,
                                                 const float* __restrict__ x,
                                                 float* __restrict__ out) {
    int lane = threadIdx.x & 63, wave = threadIdx.x >> 6;
    int l15 = lane & 15, lg = lane >> 4;
    int bi = blockIdx.x;
    int b = bi & 7;
    int slot = bi >> 3;                 // 0..127
    int m0 = (slot & 7) * 64;
    int n0 = (slot >> 3) * 64;
    int mw = (wave >> 1) * 32, nw = (wave & 1) * 32;
    const ushort* Ag = Wb + (size_t)m0 * 512;
    const ushort* Bg = aoT + (size_t)b * 524288 + (size_t)n0 * 512;

    __shared__ ushort abuf[4][2048];    // 64 x 32
    __shared__ ushort bbuf[4][2048];    // 64 x 32

    f32x4 acc[2][2] = {};
#pragma unroll
    for (int p = 0; p < 3; ++p) {
        stage_tile32(abuf[p], Ag + p * 32, 512, 4, wave, lane);
        stage_tile32(bbuf[p], Bg + p * 32, 512, 4, wave, lane);
    }
    asm volatile("s_waitcnt vmcnt(4)" ::: "memory");
    __builtin_amdgcn_s_barrier();

#pragma unroll 1
    for (int t = 0; t < 16; ++t) {
        if (t < 13) {
            int nxt = (t + 3) & 3;
            stage_tile32(abuf[nxt], Ag + (t + 3) * 32, 512, 4, wave, lane);
            stage_tile32(bbuf[nxt], Bg + (t + 3) * 32, 512, 4, wave, lane);
        }
        const ushort* A = abuf[t & 3];
        const ushort* B = bbuf[t & 3];
        bf16x8 af[2], bfr[2];
#pragma unroll
        for (int i = 0; i < 2; i++)
            af[i] = lds_read_row32(A, mw + i * 16 + l15, lg * 16);
#pragma unroll
        for (int j = 0; j < 2; j++)
            bfr[j] = lds_read_row32(B, nw + j * 16 + l15, lg * 16);
        __builtin_amdgcn_s_setprio(1);
#pragma unroll
        for (int i = 0; i < 2; i++)
#pragma unroll
            for (int j = 0; j < 2; j++)
                acc[i][j] = MFMA(af[i], bfr[j], acc[i][j]);
        __builtin_amdgcn_s_setprio(0);
        if (t < 15) {
            if (t < 13)      asm volatile("s_waitcnt vmcnt(4)" ::: "memory");
            else if (t == 13) asm volatile("s_waitcnt vmcnt(2)" ::: "memory");
            else              asm volatile("s_waitcnt vmcnt(0)" ::: "memory");
            __builtin_amdgcn_s_barrier();
        }
    }

#pragma unroll
    for (int i = 0; i < 2; i++) {
        int ob = m0 + mw + i * 16 + lg * 4;
        float bias[4];
#pragma unroll
        for (int r = 0; r < 4; r++) bias[r] = projb[ob + r];
#pragma unroll
        for (int j = 0; j < 2; j++) {
            int n = n0 + nw + j * 16 + l15;
#pragma unroll
            for (int r = 0; r < 4; r++) {
                size_t idx = (size_t)(b * 512 + ob + r) * 1024 + n;
                out[idx] = x[idx] + bias[r] + acc[i][j][r];
            }
        }
    }
}

// ---------------------------------------------------------------- launcher
extern "C" void kernel_launch(void* const* d_in, const int* in_sizes, int n_in,
                              void* d_out, int out_size, void* d_ws, size_t ws_size,
                              hipStream_t stream) {
    const float* x     = (const float*)d_in[0];
    const float* gnw   = (const float*)d_in[1];
    const float* gnb   = (const float*)d_in[2];
    const float* qkvw  = (const float*)d_in[3];
    const float* qkvb  = (const float*)d_in[4];
    const float* projw = (const float*)d_in[5];
    const float* projb = (const float*)d_in[6];
    float* out = (float*)d_out;

    char* ws = (char*)d_ws;
    ushort* hnT    = (ushort*)(ws);                          // 8 MB (reused as aoT)
    ushort* qT     = (ushort*)(ws + (size_t)(8u << 20));     // 8 MB
    ushort* kT     = (ushort*)(ws + (size_t)(16u << 20));    // 8 MB
    ushort* vbuf   = (ushort*)(ws + (size_t)(24u << 20));    // 8 MB
    ushort* qkvwb  = (ushort*)(ws + (size_t)(32u << 20));    // 1.5 MB
    ushort* projwb = (ushort*)(ws + (size_t)(32u << 20) + 1572864);  // 0.5 MB

    gn_cvt_kernel<<<dim3(768), dim3(512), 0, stream>>>(x, gnw, gnb, hnT,
                                                       qkvw, projw, qkvwb, projwb);
    gemm_qkv<<<dim3(768), dim3(256), 0, stream>>>(qkvwb, hnT, qkvb, qT, kT, vbuf);
    attn_kernel<<<dim3(512), dim3(256), 0, stream>>>(qT, kT, vbuf, hnT /* aoT */);
    gemm_proj<<<dim3(1024), dim3(256), 0, stream>>>(projwb, hnT, projb, x, out);
}

// Round 18
// 76.368 us; speedup vs baseline: 1.1885x; 1.0019x over previous
//
#include <hip/hip_runtime.h>

typedef __bf16 bf16x8 __attribute__((ext_vector_type(8)));
typedef float f32x4 __attribute__((ext_vector_type(4)));

#define MFMA(a, b, c) __builtin_amdgcn_mfma_f32_16x16x32_bf16(a, b, c, 0, 0, 0)

#define CS 0.18033688011112042f   /* 0.125 * log2(e) */

__device__ __forceinline__ ushort f2bf(float f) {
    __bf16 h = (__bf16)f;
    return *(ushort*)&h;
}
__device__ __forceinline__ float bf2f(ushort u) {
    unsigned int x = ((unsigned int)u) << 16;
    return __uint_as_float(x);
}

// ---- stage (8*nchunks)-row x 64-col bf16 tile into LDS, XOR-swizzled (128B rows)
__device__ __forceinline__ void stage_tile64(ushort* lds, const ushort* gbase,
                                             int row_stride, int nchunks,
                                             int wave, int lane) {
    int r8 = lane >> 3;
    int cswz = ((lane & 7) ^ r8) << 4;
#pragma unroll
    for (int c = wave; c < nchunks; c += 4) {
        const char* g = (const char*)(gbase + (size_t)(c * 8 + r8) * row_stride) + cswz;
        __builtin_amdgcn_global_load_lds(
            (const __attribute__((address_space(1))) unsigned int*)g,
            (__attribute__((address_space(3))) unsigned int*)((char*)lds + c * 1024),
            16, 0, 0);
    }
}

__device__ __forceinline__ bf16x8 lds_read_row(const ushort* lds, int row, int cb) {
    return *(const bf16x8*)((const char*)lds + row * 128 + (cb ^ ((row & 7) << 4)));
}

// ---- stage (16*nchunks)-row x 32-col bf16 tile into LDS, XOR-swizzled (64B rows)
__device__ __forceinline__ void stage_tile32(ushort* lds, const ushort* gbase,
                                             int row_stride, int nchunks,
                                             int wave, int lane) {
    int r16 = lane >> 2;
    int csw = (((lane & 3) ^ ((lane >> 3) & 3)) << 3);
#pragma unroll
    for (int c = wave; c < nchunks; c += 4) {
        const ushort* g = gbase + (size_t)(c * 16 + r16) * row_stride + csw;
        __builtin_amdgcn_global_load_lds(
            (const __attribute__((address_space(1))) unsigned int*)g,
            (__attribute__((address_space(3))) unsigned int*)((char*)lds + c * 1024),
            16, 0, 0);
    }
}

__device__ __forceinline__ bf16x8 lds_read_row32(const ushort* lds, int row, int cb) {
    return *(const bf16x8*)((const char*)lds + row * 64 + (cb ^ (((row >> 1) & 3) << 4)));
}

// ---------------------------------------------------------------- groupnorm (+fused weight cvt)
// 512-thread blocks: 8 waves/CU during the latency-bound 64KB fp32 read phase.
// blocks [0,256): GroupNorm per (b,g), x read ONCE (stats + bf16 tile cache in
// LDS pass 1; normalize from LDS pass 2). blocks [256,768): weight cvt.
__global__ __launch_bounds__(512) void gn_cvt_kernel(const float* __restrict__ x,
                                                     const float* __restrict__ gnw,
                                                     const float* __restrict__ gnb,
                                                     ushort* __restrict__ hnT,
                                                     const float* __restrict__ w1,
                                                     const float* __restrict__ w2,
                                                     ushort* __restrict__ o1,
                                                     ushort* __restrict__ o2) {
    __shared__ ushort xcache[16 * 1028];   // ~32.1 KB
    __shared__ float red[16];
    __shared__ float sw[16], sb[16];

    if (blockIdx.x >= 256) {
        int t = (blockIdx.x - 256) * 512 + threadIdx.x;   // 0..262143
        const int n1q = (1536 * 512) / 4;
        float4 v;
        ushort* dst;
        int idx;
        if (t < n1q) {
            v = ((const float4*)w1)[t]; dst = o1; idx = t;
        } else {
            idx = t - n1q;
            v = ((const float4*)w2)[idx]; dst = o2;
        }
        ushort4 p;
        p.x = f2bf(v.x); p.y = f2bf(v.y); p.z = f2bf(v.z); p.w = f2bf(v.w);
        ((ushort4*)dst)[idx] = p;
        return;
    }

    int b = blockIdx.x >> 5, g = blockIdx.x & 31;
    const float* xp = x + (size_t)(b * 512 + g * 16) * 1024;
    int t = threadIdx.x;

    float s = 0.f, ss = 0.f;
    const float4* xp4 = (const float4*)xp;
    for (int i = t; i < 4096; i += 512) {
        float4 v = xp4[i];
        s += (v.x + v.y) + (v.z + v.w);
        ss += (v.x * v.x + v.y * v.y) + (v.z * v.z + v.w * v.w);
        int f = i * 4;
        int cc = f >> 10, nl = f & 1023;
        ushort4 c;
        c.x = f2bf(v.x); c.y = f2bf(v.y); c.z = f2bf(v.z); c.w = f2bf(v.w);
        *(ushort4*)&xcache[cc * 1028 + nl] = c;
    }
#pragma unroll
    for (int off = 32; off >= 1; off >>= 1) {
        s += __shfl_xor(s, off);
        ss += __shfl_xor(ss, off);
    }
    int wave = t >> 6;
    if ((t & 63) == 0) { red[wave] = s; red[wave + 8] = ss; }
    if (t < 16) { sw[t] = gnw[g * 16 + t]; sb[t] = gnb[g * 16 + t]; }
    __syncthreads();
    float S = red[0] + red[1] + red[2] + red[3] + red[4] + red[5] + red[6] + red[7];
    float SS = red[8] + red[9] + red[10] + red[11] + red[12] + red[13] + red[14] + red[15];
    float mean = S * (1.0f / 16384.0f);
    float var = SS * (1.0f / 16384.0f) - mean * mean;
    float rstd = rsqrtf(var + 1e-5f);

    int cc0 = (t & 3) * 4;
    int nb = t >> 2;                        // 0..127
    float w0 = sw[cc0] * rstd, w1_ = sw[cc0 + 1] * rstd,
          w2_ = sw[cc0 + 2] * rstd, w3 = sw[cc0 + 3] * rstd;
    float b0 = sb[cc0] - mean * w0, b1 = sb[cc0 + 1] - mean * w1_,
          b2 = sb[cc0 + 2] - mean * w2_, b3 = sb[cc0 + 3] - mean * w3;
#pragma unroll
    for (int k = 0; k < 8; ++k) {
        int nl = nb + 128 * k;
        ushort4 p;
        p.x = f2bf(bf2f(xcache[(cc0 + 0) * 1028 + nl]) * w0 + b0);
        p.y = f2bf(bf2f(xcache[(cc0 + 1) * 1028 + nl]) * w1_ + b1);
        p.z = f2bf(bf2f(xcache[(cc0 + 2) * 1028 + nl]) * w2_ + b2);
        p.w = f2bf(bf2f(xcache[(cc0 + 3) * 1028 + nl]) * w3 + b3);
        *(ushort4*)(hnT + ((size_t)b * 1024 + nl) * 512 + g * 16 + cc0) = p;
    }
}

// ---------------------------------------------------------------- QKV GEMM
// BK=32, triple-buffered ring (48KB -> 3 blocks/CU), counted-vmcnt pipeline.
// V written kv-permuted (pi^-1) for attention's in-register P; Q pre-scaled.
// XCD swizzle: b = bi&7 -> batch b's Q/K/V exit through XCD b's L2.
__global__ __launch_bounds__(256, 3) void gemm_qkv(const ushort* __restrict__ Wb,
                                                   const ushort* __restrict__ hnT,
                                                   const float* __restrict__ qkvb,
                                                   ushort* __restrict__ qT,
                                                   ushort* __restrict__ kT,
                                                   ushort* __restrict__ vb) {
    int lane = threadIdx.x & 63, wave = threadIdx.x >> 6;
    int l15 = lane & 15, lg = lane >> 4;
    int bi = blockIdx.x;
    int b = bi & 7;
    int slot = bi >> 3;
    int m0 = (slot % 12) * 128;
    int n0 = (slot / 12) * 128;
    int mw = (wave >> 1) * 64, nw = (wave & 1) * 64;
    const ushort* Ag = Wb + (size_t)m0 * 512;
    const ushort* Bg = hnT + (size_t)b * 524288 + (size_t)n0 * 512;

    __shared__ ushort abuf[3][4096];
    __shared__ ushort bbuf[3][4096];

    f32x4 acc[4][4] = {};
#pragma unroll
    for (int p = 0; p < 2; ++p) {
        stage_tile32(abuf[p], Ag + p * 32, 512, 8, wave, lane);
        stage_tile32(bbuf[p], Bg + p * 32, 512, 8, wave, lane);
    }
    asm volatile("s_waitcnt vmcnt(4)" ::: "memory");
    __builtin_amdgcn_s_barrier();

    int cur = 0;
#pragma unroll 1
    for (int t = 0; t < 16; ++t) {
        if (t < 14) {
            int nxt = cur + 2; if (nxt >= 3) nxt -= 3;
            stage_tile32(abuf[nxt], Ag + (t + 2) * 32, 512, 8, wave, lane);
            stage_tile32(bbuf[nxt], Bg + (t + 2) * 32, 512, 8, wave, lane);
        }
        const ushort* A = abuf[cur];
        const ushort* B = bbuf[cur];
        bf16x8 af[4], bfr[4];
#pragma unroll
        for (int i = 0; i < 4; i++)
            af[i] = lds_read_row32(A, mw + i * 16 + l15, lg * 16);
#pragma unroll
        for (int j = 0; j < 4; j++)
            bfr[j] = lds_read_row32(B, nw + j * 16 + l15, lg * 16);
        __builtin_amdgcn_s_setprio(1);
#pragma unroll
        for (int i = 0; i < 4; i++)
#pragma unroll
            for (int j = 0; j < 4; j++)
                acc[i][j] = MFMA(af[i], bfr[j], acc[i][j]);
        __builtin_amdgcn_s_setprio(0);
        if (t < 15) {
            if (t < 14) asm volatile("s_waitcnt vmcnt(4)" ::: "memory");
            else        asm volatile("s_waitcnt vmcnt(0)" ::: "memory");
            __builtin_amdgcn_s_barrier();
        }
        cur = cur + 1; if (cur == 3) cur = 0;
    }

#pragma unroll
    for (int i = 0; i < 4; i++) {
        int ob = m0 + mw + i * 16 + lg * 4;
        float bias[4];
#pragma unroll
        for (int r = 0; r < 4; r++) bias[r] = qkvb[ob + r];
        int part = ob >> 9;
        int oo = ob & 511;
#pragma unroll
        for (int j = 0; j < 4; j++) {
            int n = n0 + nw + j * 16 + l15;
            if (part == 2) {
                int L = n & 63;
                int cf = L >> 4;
                int s = ((cf >> 1) << 5) | (((L >> 2) & 3) << 3) | ((cf & 1) << 2) | (L & 3);
                int np = (n & ~63) | s;
#pragma unroll
                for (int r = 0; r < 4; r++)
                    vb[(size_t)(b * 512 + oo + r) * 1024 + np] = f2bf(acc[i][j][r] + bias[r]);
            } else {
                ushort* dst = part ? kT : qT;
                float sc = part ? 1.0f : CS;
                int h = oo >> 6, dd = oo & 63;
                ushort4 p;
                p.x = f2bf((acc[i][j][0] + bias[0]) * sc);
                p.y = f2bf((acc[i][j][1] + bias[1]) * sc);
                p.z = f2bf((acc[i][j][2] + bias[2]) * sc);
                p.w = f2bf((acc[i][j][3] + bias[3]) * sc);
                *(ushort4*)(dst + ((size_t)((b * 8 + h) * 1024 + n)) * 64 + dd) = p;
            }
        }
    }
}

// ---------------------------------------------------------------- attention
// 128 q-rows/block (4 waves x 32 rows). K/V on a 4-buffer ring, TWO kv-tiles
// per barrier group. Swapped QK^T keeps P in registers (V kv-permuted by
// pi^-1 in gemm_qkv). Q pre-scaled: P = exp2(S). Row sums via ones-MFMA.
// XCD decode: bi&7 = b (matches gemm_qkv's writer XCD -> K/V/Q served from
// dirty L2 on the SAME XCD; aoT writes land on XCD b, matching gemm_proj).
// All 8 q-blocks of a bh still share one XCD.
__global__ __launch_bounds__(256) void attn_kernel(const ushort* __restrict__ qT,
                                                   const ushort* __restrict__ kT,
                                                   const ushort* __restrict__ vb,
                                                   ushort* __restrict__ aoT) {
    int bi = blockIdx.x;
    int bh = ((bi & 7) << 3) | (bi >> 6);
    int q0 = ((bi >> 3) & 7) * 128;
    int b = bh >> 3, h = bh & 7;
    int lane = threadIdx.x & 63, wave = threadIdx.x >> 6;
    int l15 = lane & 15, lg = lane >> 4;
    const ushort* qp = qT + (size_t)bh * 65536;
    const ushort* kp = kT + (size_t)bh * 65536;
    const ushort* vp = vb + (size_t)bh * 65536;

    __shared__ ushort kbuf[4][4096];   // [kv 64][d 64]
    __shared__ ushort vbuf[4][4096];   // [dd 64][kv-slot 64] (pi-permuted)

    bf16x8 vone;
#pragma unroll
    for (int e = 0; e < 8; e++) vone[e] = (__bf16)1.0f;

    bf16x8 qf[2][2];
#pragma unroll
    for (int i = 0; i < 2; i++)
#pragma unroll
        for (int kh = 0; kh < 2; kh++)
            qf[i][kh] = *(const bf16x8*)(qp + (size_t)(q0 + wave * 32 + i * 16 + l15) * 64 + kh * 32 + lg * 8);

    f32x4 oacc[2][4] = {};
    f32x4 lacc[2] = {};

    stage_tile64(kbuf[0], kp, 64, 8, wave, lane);
    stage_tile64(vbuf[0], vp, 1024, 8, wave, lane);
    stage_tile64(kbuf[1], kp + 4096, 64, 8, wave, lane);
    stage_tile64(vbuf[1], vp + 64, 1024, 8, wave, lane);
    asm volatile("s_waitcnt vmcnt(0)" ::: "memory");
    __builtin_amdgcn_s_barrier();

#pragma unroll 1
    for (int g = 0; g < 8; ++g) {
        int t0 = 2 * g;
        if (g < 7) {
            int na = (t0 + 2) & 3, nb2 = (t0 + 3) & 3;
            stage_tile64(kbuf[na], kp + (size_t)(t0 + 2) * 4096, 64, 8, wave, lane);
            stage_tile64(vbuf[na], vp + (t0 + 2) * 64, 1024, 8, wave, lane);
            stage_tile64(kbuf[nb2], kp + (size_t)(t0 + 3) * 4096, 64, 8, wave, lane);
            stage_tile64(vbuf[nb2], vp + (t0 + 3) * 64, 1024, 8, wave, lane);
        }
#pragma unroll
        for (int u = 0; u < 2; ++u) {
            int t = t0 + u;
            const ushort* kb = kbuf[t & 3];
            const ushort* vc = vbuf[t & 3];

            f32x4 sacc[2][4] = {};
            __builtin_amdgcn_s_setprio(1);
#pragma unroll
            for (int kh = 0; kh < 2; kh++)
#pragma unroll
                for (int cf = 0; cf < 4; cf++) {
                    bf16x8 kf = lds_read_row(kb, cf * 16 + l15, kh * 64 + lg * 16);
                    sacc[0][cf] = MFMA(kf, qf[0][kh], sacc[0][cf]);
                    sacc[1][cf] = MFMA(kf, qf[1][kh], sacc[1][cf]);
                }
            __builtin_amdgcn_s_setprio(0);

            bf16x8 vf[2][4];
#pragma unroll
            for (int ks = 0; ks < 2; ks++)
#pragma unroll
                for (int cf = 0; cf < 4; cf++)
                    vf[ks][cf] = lds_read_row(vc, cf * 16 + l15, ks * 64 + lg * 16);

            bf16x8 pa[2][2];
#pragma unroll
            for (int i = 0; i < 2; i++)
#pragma unroll
                for (int ks = 0; ks < 2; ks++) {
                    bf16x8 tr;
#pragma unroll
                    for (int jhi = 0; jhi < 2; jhi++)
#pragma unroll
                        for (int r = 0; r < 4; r++)
                            tr[jhi * 4 + r] = (__bf16)exp2f(sacc[i][ks * 2 + jhi][r]);
                    pa[i][ks] = tr;
                }

            __builtin_amdgcn_s_setprio(1);
#pragma unroll
            for (int i = 0; i < 2; i++)
#pragma unroll
                for (int ks = 0; ks < 2; ks++) {
                    lacc[i] = MFMA(pa[i][ks], vone, lacc[i]);
#pragma unroll
                    for (int cf = 0; cf < 4; cf++)
                        oacc[i][cf] = MFMA(pa[i][ks], vf[ks][cf], oacc[i][cf]);
                }
            __builtin_amdgcn_s_setprio(0);
        }
        if (g < 7) {
            asm volatile("s_waitcnt vmcnt(0)" ::: "memory");
            __builtin_amdgcn_s_barrier();
        }
    }

#pragma unroll
    for (int i = 0; i < 2; i++)
#pragma unroll
        for (int r = 0; r < 4; r++) {
            float inv = 1.0f / lacc[i][r];
            int n = q0 + wave * 32 + i * 16 + lg * 4 + r;
            size_t obase = ((size_t)b * 1024 + n) * 512 + h * 64;
#pragma unroll
            for (int cf = 0; cf < 4; cf++)
                aoT[obase + cf * 16 + l15] = f2bf(oacc[i][cf][r] * inv);
        }
}

// ---------------------------------------------------------------- proj GEMM + residual
// 64x64 tiles -> grid 1024 = 4 blocks/CU. BK=32, quad ring, counted-vmcnt.
__global__ __launch_bounds__(256) void gemm_proj(const ushort* __restrict__ Wb,
                                                 const ushort* __restrict__ aoT,
                                                 const float* __restrict__ projb,
                                                 const float* __restrict__ x,
                                                 float* __restrict__ out) {
    int lane = threadIdx.x & 63, wave = threadIdx.x >> 6;
    int l15 = lane & 15, lg = lane >> 4;
    int bi = blockIdx.x;
    int b = bi & 7;
    int slot = bi >> 3;                 // 0..127
    int m0 = (slot & 7) * 64;
    int n0 = (slot >> 3) * 64;
    int mw = (wave >> 1) * 32, nw = (wave & 1) * 32;
    const ushort* Ag = Wb + (size_t)m0 * 512;
    const ushort* Bg = aoT + (size_t)b * 524288 + (size_t)n0 * 512;

    __shared__ ushort abuf[4][2048];    // 64 x 32
    __shared__ ushort bbuf[4][2048];    // 64 x 32

    f32x4 acc[2][2] = {};
#pragma unroll
    for (int p = 0; p < 3; ++p) {
        stage_tile32(abuf[p], Ag + p * 32, 512, 4, wave, lane);
        stage_tile32(bbuf[p], Bg + p * 32, 512, 4, wave, lane);
    }
    asm volatile("s_waitcnt vmcnt(4)" ::: "memory");
    __builtin_amdgcn_s_barrier();

#pragma unroll 1
    for (int t = 0; t < 16; ++t) {
        if (t < 13) {
            int nxt = (t + 3) & 3;
            stage_tile32(abuf[nxt], Ag + (t + 3) * 32, 512, 4, wave, lane);
            stage_tile32(bbuf[nxt], Bg + (t + 3) * 32, 512, 4, wave, lane);
        }
        const ushort* A = abuf[t & 3];
        const ushort* B = bbuf[t & 3];
        bf16x8 af[2], bfr[2];
#pragma unroll
        for (int i = 0; i < 2; i++)
            af[i] = lds_read_row32(A, mw + i * 16 + l15, lg * 16);
#pragma unroll
        for (int j = 0; j < 2; j++)
            bfr[j] = lds_read_row32(B, nw + j * 16 + l15, lg * 16);
        __builtin_amdgcn_s_setprio(1);
#pragma unroll
        for (int i = 0; i < 2; i++)
#pragma unroll
            for (int j = 0; j < 2; j++)
                acc[i][j] = MFMA(af[i], bfr[j], acc[i][j]);
        __builtin_amdgcn_s_setprio(0);
        if (t < 15) {
            if (t < 13)      asm volatile("s_waitcnt vmcnt(4)" ::: "memory");
            else if (t == 13) asm volatile("s_waitcnt vmcnt(2)" ::: "memory");
            else              asm volatile("s_waitcnt vmcnt(0)" ::: "memory");
            __builtin_amdgcn_s_barrier();
        }
    }

#pragma unroll
    for (int i = 0; i < 2; i++) {
        int ob = m0 + mw + i * 16 + lg * 4;
        float bias[4];
#pragma unroll
        for (int r = 0; r < 4; r++) bias[r] = projb[ob + r];
#pragma unroll
        for (int j = 0; j < 2; j++) {
            int n = n0 + nw + j * 16 + l15;
#pragma unroll
            for (int r = 0; r < 4; r++) {
                size_t idx = (size_t)(b * 512 + ob + r) * 1024 + n;
                out[idx] = x[idx] + bias[r] + acc[i][j][r];
            }
        }
    }
}

// ---------------------------------------------------------------- launcher
extern "C" void kernel_launch(void* const* d_in, const int* in_sizes, int n_in,
                              void* d_out, int out_size, void* d_ws, size_t ws_size,
                              hipStream_t stream) {
    const float* x     = (const float*)d_in[0];
    const float* gnw   = (const float*)d_in[1];
    const float* gnb   = (const float*)d_in[2];
    const float* qkvw  = (const float*)d_in[3];
    const float* qkvb  = (const float*)d_in[4];
    const float* projw = (const float*)d_in[5];
    const float* projb = (const float*)d_in[6];
    float* out = (float*)d_out;

    char* ws = (char*)d_ws;
    ushort* hnT    = (ushort*)(ws);                          // 8 MB (reused as aoT)
    ushort* qT     = (ushort*)(ws + (size_t)(8u << 20));     // 8 MB
    ushort* kT     = (ushort*)(ws + (size_t)(16u << 20));    // 8 MB
    ushort* vbuf   = (ushort*)(ws + (size_t)(24u << 20));    // 8 MB
    ushort* qkvwb  = (ushort*)(ws + (size_t)(32u << 20));    // 1.5 MB
    ushort* projwb = (ushort*)(ws + (size_t)(32u << 20) + 1572864);  // 0.5 MB

    gn_cvt_kernel<<<dim3(768), dim3(512), 0, stream>>>(x, gnw, gnb, hnT,
                                                       qkvw, projw, qkvwb, projwb);
    gemm_qkv<<<dim3(768), dim3(256), 0, stream>>>(qkvwb, hnT, qkvb, qT, kT, vbuf);
    attn_kernel<<<dim3(512), dim3(256), 0, stream>>>(qT, kT, vbuf, hnT /* aoT */);
    gemm_proj<<<dim3(1024), dim3(256), 0, stream>>>(projwb, hnT, projb, x, out);
}